// Round 2
// baseline (244.280 us; speedup 1.0000x reference)
//
#include <hip/hip_runtime.h>
#include <hip/hip_bf16.h>

#define BATCH 8
#define SEQ   2048
#define DIM   64

typedef __attribute__((ext_vector_type(8))) short short8;
typedef __attribute__((ext_vector_type(4))) float floatx4;

static __device__ __forceinline__ unsigned short f2bf(float x) {
    union { float f; unsigned u; } v; v.f = x;
    unsigned r = (v.u + 0x7FFFu + ((v.u >> 16) & 1u)) >> 16;
    return (unsigned short)r;
}

// ---- fused prep: Q/K bf16 casts + row norms | V transpose | V col-sums ----
// grid = 8192 (row blocks) + 256 (vt tiles) + 8 (colsum blocks)
#define NROW_BLK 8192
#define NVT_BLK  256

__global__ __launch_bounds__(256) void prep_all(
        const float* __restrict__ Q, const float* __restrict__ K,
        const float* __restrict__ V,
        unsigned short* __restrict__ Qb, unsigned short* __restrict__ Kb,
        unsigned short* __restrict__ Vt,
        float* __restrict__ q2, float* __restrict__ k2,
        float* __restrict__ csum) {
    int bid = blockIdx.x;
    if (bid < NROW_BLK) {
        // ---- bf16 casts of Q,K rows + squared row norms (1 wave = 1 row) ----
        int wid  = bid * 4 + (threadIdx.x >> 6);
        int lane = threadIdx.x & 63;
        const float* src; unsigned short* db; float* dn; int row;
        if (wid < BATCH * SEQ) { src = Q; db = Qb; dn = q2; row = wid; }
        else                   { src = K; db = Kb; dn = k2; row = wid - BATCH * SEQ; }
        float v = src[(size_t)row * DIM + lane];
        db[(size_t)row * DIM + lane] = f2bf(v);
        float s = v * v;
        #pragma unroll
        for (int off = 32; off; off >>= 1) s += __shfl_xor(s, off);
        if (lane == 0) dn[row] = s;
    } else if (bid < NROW_BLK + NVT_BLK) {
        // ---- V -> Vt[b][d][t] bf16 (transposed) ----
        __shared__ float tile[64][65];
        int vb = bid - NROW_BLK;
        int b  = vb >> 5;
        int t0 = (vb & 31) * 64;
        int i  = threadIdx.x;
        int d  = i & 63, g = i >> 6;
        #pragma unroll
        for (int p = 0; p < 16; ++p) {
            int tt = p * 4 + g;
            tile[tt][d] = V[((size_t)(b * SEQ + t0 + tt)) * DIM + d];
        }
        __syncthreads();
        int tt = i & 63;
        #pragma unroll
        for (int p = 0; p < 16; ++p) {
            int dd = p * 4 + g;
            Vt[((size_t)(b * DIM + dd)) * SEQ + t0 + tt] = f2bf(tile[tt][dd]);
        }
    } else {
        // ---- per-batch V column sums (atomic-free) ----
        __shared__ float psum[4][64];
        int b = bid - NROW_BLK - NVT_BLK;
        int i = threadIdx.x;
        int d = i & 63, g = i >> 6;
        float s = 0.f;
        for (int t = g; t < SEQ; t += 4)
            s += V[((size_t)(b * SEQ + t)) * DIM + d];
        psum[g][d] = s;
        __syncthreads();
        if (i < 64)
            csum[b * DIM + i] = psum[0][i] + psum[1][i] + psum[2][i] + psum[3][i];
    }
}

// ---- main: flash-style shifted-softmax gaussian attention -----------------
// block = 4 waves; wave w owns 16 q-rows; 64-wide K/V tiles staged in LDS.
// P' = exp(w)-1 in bf16 keeps the softmax signal (p ~ 1+1e-5 would flush).
// TSPLIT: key-range split across blocks for occupancy; partials to ws.
template <int TSPLIT>
__global__ __launch_bounds__(256) void gauss_attn(
        const unsigned short* __restrict__ Qb, const unsigned short* __restrict__ Kb,
        const unsigned short* __restrict__ Vt, const float* __restrict__ q2,
        const float* __restrict__ k2, const float* __restrict__ csum,
        float* __restrict__ nbuf, float* __restrict__ dbuf,
        float* __restrict__ out) {
    // stride 72 (=64+8): 16B-aligned rows, 2-way bank aliasing on b128 reads (free)
    __shared__ __align__(16) unsigned short Klds[64 * 72];
    __shared__ __align__(16) unsigned short Vlds[64 * 72];
    __shared__ __align__(16) unsigned short Plds[4][16 * 72];
    __shared__ float k2lds[64];

    const int bid  = blockIdx.x;
    const int ts   = bid % TSPLIT;
    const int qt   = bid / TSPLIT;
    const int b    = qt >> 5;
    const int q0   = (qt & 31) * 64;
    const int tid  = threadIdx.x;
    const int w    = tid >> 6;
    const int lane = tid & 63;
    const int l15  = lane & 15;
    const int quad = lane >> 4;
    const int qrow0 = q0 + w * 16;
    const int TCHUNK = SEQ / TSPLIT;

    // Q fragments (A operand): A[m=lane&15][k=quad*8+j]
    short8 qf[2];
    #pragma unroll
    for (int kc = 0; kc < 2; ++kc)
        qf[kc] = *(const short8*)(Qb + ((size_t)(b * SEQ + qrow0 + l15)) * DIM + kc * 32 + quad * 8);
    floatx4 q2v = *(const floatx4*)(q2 + b * SEQ + qrow0 + quad * 4);

    floatx4 acc[4]; floatx4 den;
    #pragma unroll
    for (int nt = 0; nt < 4; ++nt) acc[nt] = (floatx4){0.f, 0.f, 0.f, 0.f};
    den = (floatx4){0.f, 0.f, 0.f, 0.f};

    // ones B-fragment: column n=0 all ones -> row sums of P' land in col 0
    short8 ones;
    {
        short o = (l15 == 0) ? (short)0x3F80 : (short)0;
        #pragma unroll
        for (int j = 0; j < 8; ++j) ones[j] = o;
    }

    unsigned short* Pw = Plds[w];

    for (int t0 = ts * TCHUNK; t0 < (ts + 1) * TCHUNK; t0 += 64) {
        // ---- stage K tile (row-major) and Vt tile (d-major) ----
        {
            int tt = tid >> 3, dg = tid & 7;
            *(uint4*)&Klds[tt * 72 + dg * 8] =
                *(const uint4*)(Kb + ((size_t)(b * SEQ + t0 + tt)) * DIM + dg * 8);
            *(uint4*)&Klds[(tt + 32) * 72 + dg * 8] =
                *(const uint4*)(Kb + ((size_t)(b * SEQ + t0 + tt + 32)) * DIM + dg * 8);
            *(uint4*)&Vlds[tt * 72 + dg * 8] =
                *(const uint4*)(Vt + ((size_t)(b * DIM + tt)) * SEQ + t0 + dg * 8);
            *(uint4*)&Vlds[(tt + 32) * 72 + dg * 8] =
                *(const uint4*)(Vt + ((size_t)(b * DIM + tt + 32)) * SEQ + t0 + dg * 8);
            if (tid < 64) k2lds[tid] = k2[b * SEQ + t0 + tid];
        }
        __syncthreads();

        // ---- QK^T (B^T pattern) + scoring, write P' bf16 to LDS ----
        #pragma unroll
        for (int nt = 0; nt < 4; ++nt) {
            short8 kf0 = *(const short8*)&Klds[(nt * 16 + l15) * 72 + 0 * 32 + quad * 8];
            short8 kf1 = *(const short8*)&Klds[(nt * 16 + l15) * 72 + 1 * 32 + quad * 8];
            floatx4 sc = (floatx4){0.f, 0.f, 0.f, 0.f};
            sc = __builtin_amdgcn_mfma_f32_16x16x32_bf16(qf[0], kf0, sc, 0, 0, 0);
            sc = __builtin_amdgcn_mfma_f32_16x16x32_bf16(qf[1], kf1, sc, 0, 0, 0);
            float k2n = k2lds[nt * 16 + l15];
            #pragma unroll
            for (int r = 0; r < 4; ++r) {
                float d2   = fmaxf(fmaf(-2.f, sc[r], q2v[r] + k2n), 0.f);
                float dist = sqrtf(d2);
                float wgt  = __expf(-dist);
                float e1 = __expf(wgt) - 1.f;
                float pl = wgt * fmaf(wgt, fmaf(wgt, 0.16666667f, 0.5f), 1.f);
                float pv = (wgt > 0.03f) ? e1 : pl;
                Pw[(quad * 4 + r) * 72 + nt * 16 + l15] = f2bf(pv);
            }
        }

        // ---- P'V + row-sum(P') via ones column ----
        #pragma unroll
        for (int tc = 0; tc < 2; ++tc) {
            short8 pf = *(const short8*)&Pw[l15 * 72 + tc * 32 + quad * 8];
            #pragma unroll
            for (int nt = 0; nt < 4; ++nt) {
                short8 vf = *(const short8*)&Vlds[(nt * 16 + l15) * 72 + tc * 32 + quad * 8];
                acc[nt] = __builtin_amdgcn_mfma_f32_16x16x32_bf16(pf, vf, acc[nt], 0, 0, 0);
            }
            den = __builtin_amdgcn_mfma_f32_16x16x32_bf16(pf, ones, den, 0, 0, 0);
        }
        __syncthreads();
    }

    if (TSPLIT == 1) {
        // ---- single-pass epilogue: out = (csumV + P'V) / (S + rowsum P') ----
        float rcp[4];
        #pragma unroll
        for (int r = 0; r < 4; ++r) {
            float rs = __shfl(den[r], lane & 48);   // broadcast col-0 lane of this quad
            rcp[r] = 1.f / (2048.f + rs);
        }
        #pragma unroll
        for (int nt = 0; nt < 4; ++nt) {
            float cs = csum[b * DIM + nt * 16 + l15];
            #pragma unroll
            for (int r = 0; r < 4; ++r) {
                out[((size_t)(b * SEQ + qrow0 + quad * 4 + r)) * DIM + nt * 16 + l15] =
                    (cs + acc[nt][r]) * rcp[r];
            }
        }
    } else {
        // ---- write partials: numerator [ts][b][s][d], denominator [ts][b][s] ----
        float* nb = nbuf + (size_t)ts * (BATCH * SEQ * DIM);
        float* db = dbuf + (size_t)ts * (BATCH * SEQ);
        if (l15 == 0) {
            #pragma unroll
            for (int r = 0; r < 4; ++r)
                db[b * SEQ + qrow0 + quad * 4 + r] = den[r];
        }
        #pragma unroll
        for (int nt = 0; nt < 4; ++nt) {
            #pragma unroll
            for (int r = 0; r < 4; ++r) {
                nb[((size_t)(b * SEQ + qrow0 + quad * 4 + r)) * DIM + nt * 16 + l15] =
                    acc[nt][r];
            }
        }
    }
}

// ---- finalize: out = (csum + sum_ts num) / (S + sum_ts den) ---------------
template <int TSPLIT>
__global__ __launch_bounds__(256) void finalize(
        const float* __restrict__ nbuf, const float* __restrict__ dbuf,
        const float* __restrict__ csum, float* __restrict__ out) {
    int gid = blockIdx.x * 256 + threadIdx.x;   // one float4 of d per thread
    int row = gid >> 4;                          // b*SEQ + s
    int dq  = gid & 15;
    int b   = row >> 11;
    float den = 2048.f;
    #pragma unroll
    for (int t = 0; t < TSPLIT; ++t) den += dbuf[t * (BATCH * SEQ) + row];
    float rcp = 1.f / den;
    float4 n = *(const float4*)(csum + b * DIM + dq * 4);
    #pragma unroll
    for (int t = 0; t < TSPLIT; ++t) {
        float4 p = *(const float4*)(nbuf + (size_t)t * (BATCH * SEQ * DIM) + (size_t)row * DIM + dq * 4);
        n.x += p.x; n.y += p.y; n.z += p.z; n.w += p.w;
    }
    float4 o = {n.x * rcp, n.y * rcp, n.z * rcp, n.w * rcp};
    *(float4*)(out + (size_t)row * DIM + dq * 4) = o;
}

extern "C" void kernel_launch(void* const* d_in, const int* in_sizes, int n_in,
                              void* d_out, int out_size, void* d_ws, size_t ws_size,
                              hipStream_t stream) {
    const float* Q = (const float*)d_in[0];
    const float* K = (const float*)d_in[1];
    const float* V = (const float*)d_in[2];
    float* out = (float*)d_out;

    char* ws = (char*)d_ws;
    unsigned short* Qb = (unsigned short*)(ws);                        // 2 MB
    unsigned short* Kb = (unsigned short*)(ws + (2u << 20));           // 2 MB
    unsigned short* Vt = (unsigned short*)(ws + (4u << 20));           // 2 MB
    float* q2   = (float*)(ws + (6u << 20));                           // 64 KB
    float* k2   = (float*)(ws + (6u << 20) + (64u << 10));             // 64 KB
    float* csum = (float*)(ws + (6u << 20) + (128u << 10));            // pad to 64 KB
    float* nbuf = (float*)(ws + (6u << 20) + (192u << 10));            // 4*4 MB
    float* dbuf = (float*)(ws + (6u << 20) + (192u << 10) + (16u << 20)); // 4*64 KB

    const size_t need4 = (6u << 20) + (192u << 10) + (16u << 20) + (256u << 10);

    prep_all<<<NROW_BLK + NVT_BLK + BATCH, 256, 0, stream>>>(
        Q, K, V, Qb, Kb, Vt, q2, k2, csum);

    if (ws_size >= need4) {
        gauss_attn<4><<<BATCH * 32 * 4, 256, 0, stream>>>(
            Qb, Kb, Vt, q2, k2, csum, nbuf, dbuf, out);
        finalize<4><<<(BATCH * SEQ * DIM / 4) / 256, 256, 0, stream>>>(
            nbuf, dbuf, csum, out);
    } else {
        gauss_attn<1><<<BATCH * 32, 256, 0, stream>>>(
            Qb, Kb, Vt, q2, k2, csum, nbuf, dbuf, out);
    }
}

// Round 3
// 131.521 us; speedup vs baseline: 1.8574x; 1.8574x over previous
//
#include <hip/hip_runtime.h>
#include <hip/hip_bf16.h>

#define BATCH 8
#define SEQ   2048
#define DIM   64

typedef __attribute__((ext_vector_type(8))) short short8;
typedef __attribute__((ext_vector_type(4))) float floatx4;

static __device__ __forceinline__ unsigned short f2bf(float x) {
    union { float f; unsigned u; } v; v.f = x;
    unsigned r = (v.u + 0x7FFFu + ((v.u >> 16) & 1u)) >> 16;
    return (unsigned short)r;
}

// ---- fused prep ------------------------------------------------------------
// blocks [0, 2048): Q/K bf16 cast (thread-per-float4, coalesced) + row norms
// blocks [2048, 2304): V -> Vt[b][d][t] bf16 transpose + csum atomics
#define QK_BLK 2048
#define VT_BLK 256

__global__ __launch_bounds__(256) void prep_all(
        const float* __restrict__ Q, const float* __restrict__ K,
        const float* __restrict__ V,
        unsigned short* __restrict__ Qb, unsigned short* __restrict__ Kb,
        unsigned short* __restrict__ Vt,
        float* __restrict__ q2, float* __restrict__ k2,
        float* __restrict__ csum) {
    int bid = blockIdx.x;
    if (bid < QK_BLK) {
        // one float4 per thread; 16 threads per row; row norm via 16-lane shuffle
        int gid = bid * 256 + threadIdx.x;
        const int NQ = BATCH * SEQ * (DIM / 4);   // 262144 float4s in Q
        const float* src; unsigned short* db; float* dn; int idx;
        if (gid < NQ) { src = Q; db = Qb; dn = q2; idx = gid; }
        else          { src = K; db = Kb; dn = k2; idx = gid - NQ; }
        float4 v = ((const float4*)src)[idx];
        ushort4 o;
        o.x = f2bf(v.x); o.y = f2bf(v.y); o.z = f2bf(v.z); o.w = f2bf(v.w);
        ((ushort4*)db)[idx] = o;
        float s = v.x * v.x + v.y * v.y + v.z * v.z + v.w * v.w;
        s += __shfl_xor(s, 1); s += __shfl_xor(s, 2);
        s += __shfl_xor(s, 4); s += __shfl_xor(s, 8);
        if ((idx & 15) == 0) dn[idx >> 4] = s;
    } else {
        // V transpose tile + per-tile column partial sums (atomicAdd to csum)
        __shared__ float tile[64][65];
        __shared__ float psum[4][64];
        int vb = bid - QK_BLK;
        int b  = vb >> 5;
        int t0 = (vb & 31) * 64;
        int i  = threadIdx.x;
        int d  = i & 63, g = i >> 6;
        float part = 0.f;
        #pragma unroll
        for (int p = 0; p < 16; ++p) {
            int tt = p * 4 + g;
            float v = V[((size_t)(b * SEQ + t0 + tt)) * DIM + d];
            tile[tt][d] = v;
            part += v;
        }
        psum[g][d] = part;
        __syncthreads();
        int tt = i & 63;
        #pragma unroll
        for (int p = 0; p < 16; ++p) {
            int dd = p * 4 + g;
            Vt[((size_t)(b * DIM + dd)) * SEQ + t0 + tt] = f2bf(tile[tt][dd]);
        }
        if (i < 64)
            atomicAdd(&csum[b * DIM + i],
                      psum[0][i] + psum[1][i] + psum[2][i] + psum[3][i]);
    }
}

// ---- main: shifted-softmax gaussian attention ------------------------------
// Grid = B*128 blocks; block = one 16-row Q tile, 4 waves; wave w covers keys
// [w*512,(w+1)*512). K/V fragments read directly from global (L1/L2-hot);
// P' round-trips a PER-WAVE LDS slice -> no __syncthreads in the main loop.
// Final cross-wave combine via LDS. P' = exp(w)-1 keeps softmax signal in bf16.
__global__ __launch_bounds__(256, 4) void gauss_attn(
        const unsigned short* __restrict__ Qb, const unsigned short* __restrict__ Kb,
        const unsigned short* __restrict__ Vt, const float* __restrict__ q2,
        const float* __restrict__ k2, const float* __restrict__ csum,
        float* __restrict__ out) {
    __shared__ __align__(16) unsigned short Plds[4][16 * 72];
    __shared__ float abuf[4][16][68];   // +4 pad: epilogue stores ~conflict-free
    __shared__ float dbuf[4][16];

    const int b     = blockIdx.x >> 7;
    const int qrow0 = (blockIdx.x & 127) * 16;
    const int tid   = threadIdx.x;
    const int w     = tid >> 6;
    const int lane  = tid & 63;
    const int l15   = lane & 15;
    const int quad  = lane >> 4;

    const unsigned short* Kbb = Kb + (size_t)b * SEQ * DIM;
    const unsigned short* Vtb = Vt + (size_t)b * DIM * SEQ;
    const float* k2b = k2 + b * SEQ;

    // Q fragments (A operand): A[m=lane&15][k=quad*8+j]
    short8 qf[2];
    #pragma unroll
    for (int kc = 0; kc < 2; ++kc)
        qf[kc] = *(const short8*)(Qb + ((size_t)(b * SEQ + qrow0 + l15)) * DIM + kc * 32 + quad * 8);
    floatx4 q2v = *(const floatx4*)(q2 + b * SEQ + qrow0 + quad * 4);

    floatx4 acc[4]; floatx4 den;
    #pragma unroll
    for (int nt = 0; nt < 4; ++nt) acc[nt] = (floatx4){0.f, 0.f, 0.f, 0.f};
    den = (floatx4){0.f, 0.f, 0.f, 0.f};

    // ones B-fragment: column n=0 all ones -> row sums of P' land in col 0
    short8 ones;
    {
        short o = (l15 == 0) ? (short)0x3F80 : (short)0;
        #pragma unroll
        for (int j = 0; j < 8; ++j) ones[j] = o;
    }

    unsigned short* Pw = Plds[w];
    const int tbeg = w * (SEQ / 4);
    const int tend = tbeg + (SEQ / 4);

    for (int t0 = tbeg; t0 < tend; t0 += 64) {
        // ---- QK^T (B^T pattern) + scoring, P' bf16 to per-wave LDS ----
        #pragma unroll
        for (int nt = 0; nt < 4; ++nt) {
            const unsigned short* kr = Kbb + (size_t)(t0 + nt * 16 + l15) * DIM + quad * 8;
            short8 kf0 = *(const short8*)(kr);
            short8 kf1 = *(const short8*)(kr + 32);
            floatx4 sc = (floatx4){0.f, 0.f, 0.f, 0.f};
            sc = __builtin_amdgcn_mfma_f32_16x16x32_bf16(qf[0], kf0, sc, 0, 0, 0);
            sc = __builtin_amdgcn_mfma_f32_16x16x32_bf16(qf[1], kf1, sc, 0, 0, 0);
            float k2n = k2b[t0 + nt * 16 + l15];
            #pragma unroll
            for (int r = 0; r < 4; ++r) {
                float d2   = fmaxf(fmaf(-2.f, sc[r], q2v[r] + k2n), 0.f);
                float dist = sqrtf(d2);
                float wgt  = __expf(-dist);
                // expm1(wgt) ~= cubic series; exact-exp branch is ~8-sigma rare
                float pv = wgt * fmaf(wgt, fmaf(wgt, 0.16666667f, 0.5f), 1.f);
                if (__any(wgt > 0.03f)) {
                    float e1 = __expf(wgt) - 1.f;
                    pv = (wgt > 0.03f) ? e1 : pv;
                }
                Pw[(quad * 4 + r) * 72 + nt * 16 + l15] = f2bf(pv);
            }
        }

        // ---- P'V + row-sum(P') via ones column (V frags direct from global) ----
        #pragma unroll
        for (int tc = 0; tc < 2; ++tc) {
            short8 pf = *(const short8*)&Pw[l15 * 72 + tc * 32 + quad * 8];
            #pragma unroll
            for (int nt = 0; nt < 4; ++nt) {
                const unsigned short* vr =
                    Vtb + (size_t)(nt * 16 + l15) * SEQ + t0 + tc * 32 + quad * 8;
                short8 vf = *(const short8*)vr;
                acc[nt] = __builtin_amdgcn_mfma_f32_16x16x32_bf16(pf, vf, acc[nt], 0, 0, 0);
            }
            den = __builtin_amdgcn_mfma_f32_16x16x32_bf16(pf, ones, den, 0, 0, 0);
        }
    }

    // ---- cross-wave combine: acc/den -> LDS -> out ----
    #pragma unroll
    for (int nt = 0; nt < 4; ++nt)
        #pragma unroll
        for (int r = 0; r < 4; ++r)
            abuf[w][quad * 4 + r][nt * 16 + l15] = acc[nt][r];
    if (l15 == 0) {
        #pragma unroll
        for (int r = 0; r < 4; ++r) dbuf[w][quad * 4 + r] = den[r];
    }
    __syncthreads();

    float cs = csum[b * DIM + lane];
    #pragma unroll
    for (int r = 0; r < 4; ++r) {
        int row = w * 4 + r;
        float s = abuf[0][row][lane] + abuf[1][row][lane]
                + abuf[2][row][lane] + abuf[3][row][lane];
        float dn = 2048.f + dbuf[0][row] + dbuf[1][row]
                 + dbuf[2][row] + dbuf[3][row];
        out[((size_t)(b * SEQ + qrow0 + row)) * DIM + lane] = (cs + s) / dn;
    }
}

extern "C" void kernel_launch(void* const* d_in, const int* in_sizes, int n_in,
                              void* d_out, int out_size, void* d_ws, size_t ws_size,
                              hipStream_t stream) {
    const float* Q = (const float*)d_in[0];
    const float* K = (const float*)d_in[1];
    const float* V = (const float*)d_in[2];
    float* out = (float*)d_out;

    char* ws = (char*)d_ws;
    unsigned short* Qb = (unsigned short*)(ws);                        // 2 MB
    unsigned short* Kb = (unsigned short*)(ws + (2u << 20));           // 2 MB
    unsigned short* Vt = (unsigned short*)(ws + (4u << 20));           // 2 MB
    float* q2   = (float*)(ws + (6u << 20));                           // 64 KB
    float* k2   = (float*)(ws + (6u << 20) + (64u << 10));             // 64 KB
    float* csum = (float*)(ws + (6u << 20) + (128u << 10));            // 2 KB

    hipMemsetAsync(csum, 0, BATCH * DIM * sizeof(float), stream);
    prep_all<<<QK_BLK + VT_BLK, 256, 0, stream>>>(
        Q, K, V, Qb, Kb, Vt, q2, k2, csum);
    gauss_attn<<<BATCH * 128, 256, 0, stream>>>(
        Qb, Kb, Vt, q2, k2, csum, out);
}